// Round 1
// baseline (921.129 us; speedup 1.0000x reference)
//
#include <hip/hip_runtime.h>
#include <math.h>

// Problem constants (fixed by the reference)
#define BS 4
#define DD 128
#define NN 65536
#define RR 8
#define NSTEPS 6
#define EPSV 1e-6f

// Big-kernel config: 256 threads, 2 n-columns per thread (float2 loads)
#define TPB 256
#define NPT 2
#define NTILE (TPB * NPT)      // 512 columns per block
#define NBLK (NN / NTILE)      // 128 blocks per batch
#define NWAVE (TPB / 64)       // 4 waves per block

// ---------------------------------------------------------------------------
// 8-value transpose-reduce within each 8-lane group.
// Input: p[0..7] per lane. Output: sum over the lane's 8-lane group of
// p[lane & 7]  (i.e. lane l ends owning index r = l%8).
// ---------------------------------------------------------------------------
__device__ __forceinline__ float red8(const float p[8]) {
  const int l = threadIdx.x & 63;
  float t0 = p[0] + __shfl_xor(p[0], 1);
  float t1 = p[1] + __shfl_xor(p[1], 1);
  float t2 = p[2] + __shfl_xor(p[2], 1);
  float t3 = p[3] + __shfl_xor(p[3], 1);
  float t4 = p[4] + __shfl_xor(p[4], 1);
  float t5 = p[5] + __shfl_xor(p[5], 1);
  float t6 = p[6] + __shfl_xor(p[6], 1);
  float t7 = p[7] + __shfl_xor(p[7], 1);
  const bool s0 = (l & 1) != 0;
  float a0 = s0 ? t1 : t0;
  float a1 = s0 ? t3 : t2;
  float a2 = s0 ? t5 : t4;
  float a3 = s0 ? t7 : t6;
  float u0 = a0 + __shfl_xor(a0, 2);
  float u1 = a1 + __shfl_xor(a1, 2);
  float u2 = a2 + __shfl_xor(a2, 2);
  float u3 = a3 + __shfl_xor(a3, 2);
  const bool s1 = (l & 2) != 0;
  float c0 = s1 ? u1 : u0;
  float c1 = s1 ? u3 : u2;
  float w0 = c0 + __shfl_xor(c0, 4);
  float w1 = c1 + __shfl_xor(c1, 4);
  return (l & 4) ? w1 : w0;
}

// finish the reduction across the 8 groups of a 64-lane wave
__device__ __forceinline__ float wave_red(float v) {
  v += __shfl_xor(v, 8);
  v += __shfl_xor(v, 16);
  v += __shfl_xor(v, 32);
  return v;
}

// ---------------------------------------------------------------------------
// k_init: normalize bases_init (L2 over D), compute BtB, zero accumulators.
// grid = BS blocks, 128 threads (thread = d).
// ---------------------------------------------------------------------------
__global__ __launch_bounds__(128) void k_init(
    const float* __restrict__ bi, float* __restrict__ bases,
    float* __restrict__ btb, float* __restrict__ n2acc,
    float* __restrict__ ctcacc) {
  const int b = blockIdx.x;
  const int d = threadIdx.x;
  __shared__ float nb[DD][RR];
  __shared__ float norms[RR];

  float v[RR];
  {
    const float4* s4 = reinterpret_cast<const float4*>(bi + ((size_t)b * DD + d) * RR);
    float4 x0 = s4[0], x1 = s4[1];
    v[0] = x0.x; v[1] = x0.y; v[2] = x0.z; v[3] = x0.w;
    v[4] = x1.x; v[5] = x1.y; v[6] = x1.z; v[7] = x1.w;
  }
#pragma unroll
  for (int r = 0; r < RR; ++r) nb[d][r] = v[r] * v[r];
  __syncthreads();
  if (d < RR) {
    float s = 0.f;
    for (int dd = 0; dd < DD; ++dd) s += nb[dd][d];
    norms[d] = fmaxf(sqrtf(s), 1e-12f);
  }
  __syncthreads();
#pragma unroll
  for (int r = 0; r < RR; ++r) v[r] = v[r] / norms[r];
  {
    float4* o4 = reinterpret_cast<float4*>(bases + ((size_t)b * DD + d) * RR);
    o4[0] = make_float4(v[0], v[1], v[2], v[3]);
    o4[1] = make_float4(v[4], v[5], v[6], v[7]);
  }
#pragma unroll
  for (int r = 0; r < RR; ++r) nb[d][r] = v[r];
  __syncthreads();
  if (d < 64) {
    const int r = d >> 3, s2 = d & 7;
    float acc = 0.f;
    for (int dd = 0; dd < DD; ++dd) acc += nb[dd][r] * nb[dd][s2];
    btb[b * 64 + d] = acc;
    ctcacc[b * 64 + d] = 0.f;
  }
  for (int i = d; i < DD * RR; i += 128) n2acc[b * DD * RR + i] = 0.f;
}

// ---------------------------------------------------------------------------
// k_step<INIT>: per batch, per 512-column tile:
//   s = xf^T * bases            (pass 1 over xf)
//   coef_new = (INIT ? softmax(s) : coef_old) * s / (coef_old@BtB + eps)
//   store coef_new
//   accumulate numer2 += xf * coef_new (pass 2, cache-served) and
//              CtC    += coef_new^T coef_new  via butterfly + atomics
// grid = (NBLK, BS), TPB threads.
// ---------------------------------------------------------------------------
template <bool INIT>
__global__ __launch_bounds__(TPB) void k_step(
    const float* __restrict__ xf, float* __restrict__ coef,
    const float* __restrict__ bases, const float* __restrict__ btb,
    float* __restrict__ n2acc, float* __restrict__ ctcacc) {
  const int b = blockIdx.y;
  const int tid = threadIdx.x;
  const int lane = tid & 63;
  const int wv = tid >> 6;
  const size_t n0 = (size_t)blockIdx.x * NTILE + (size_t)tid * NPT;
  const float* __restrict__ xb = xf + (size_t)b * DD * NN;

  __shared__ float bl[DD][RR];        // 4 KB
  __shared__ float btbl[RR * RR];     // 256 B
  __shared__ float nlds[NWAVE][DD][RR]; // 16 KB
  __shared__ float ctcl[NWAVE][64];   // 1 KB

  reinterpret_cast<float4*>(&bl[0][0])[tid] =
      reinterpret_cast<const float4*>(bases + (size_t)b * DD * RR)[tid];
  if (tid < 64) btbl[tid] = btb[b * 64 + tid];
  __syncthreads();

  // ---- pass 1: s = xf^T bases
  float s[NPT][RR];
#pragma unroll
  for (int j = 0; j < NPT; ++j)
#pragma unroll
    for (int r = 0; r < RR; ++r) s[j][r] = 0.f;

#pragma unroll 4
  for (int d = 0; d < DD; ++d) {
    const float2 xv = *reinterpret_cast<const float2*>(xb + (size_t)d * NN + n0);
    const float4 b03 = *reinterpret_cast<const float4*>(&bl[d][0]);
    const float4 b47 = *reinterpret_cast<const float4*>(&bl[d][4]);
    float bv[RR] = {b03.x, b03.y, b03.z, b03.w, b47.x, b47.y, b47.z, b47.w};
#pragma unroll
    for (int r = 0; r < RR; ++r) {
      s[0][r] = fmaf(xv.x, bv[r], s[0][r]);
      s[1][r] = fmaf(xv.y, bv[r], s[1][r]);
    }
  }

  // ---- coef update
  float* cp = coef + ((size_t)b * NN + n0) * RR;
  float c[NPT][RR];
  if (INIT) {
#pragma unroll
    for (int j = 0; j < NPT; ++j) {
      float m = s[j][0];
#pragma unroll
      for (int r = 1; r < RR; ++r) m = fmaxf(m, s[j][r]);
      float sum = 0.f;
#pragma unroll
      for (int r = 0; r < RR; ++r) {
        float e = __expf(s[j][r] - m);
        c[j][r] = e;
        sum += e;
      }
#pragma unroll
      for (int r = 0; r < RR; ++r) c[j][r] = c[j][r] / sum;
    }
  } else {
    const float4* c4 = reinterpret_cast<const float4*>(cp);
    float4 q0 = c4[0], q1 = c4[1], q2 = c4[2], q3 = c4[3];
    c[0][0] = q0.x; c[0][1] = q0.y; c[0][2] = q0.z; c[0][3] = q0.w;
    c[0][4] = q1.x; c[0][5] = q1.y; c[0][6] = q1.z; c[0][7] = q1.w;
    c[1][0] = q2.x; c[1][1] = q2.y; c[1][2] = q2.z; c[1][3] = q2.w;
    c[1][4] = q3.x; c[1][5] = q3.y; c[1][6] = q3.z; c[1][7] = q3.w;
  }
#pragma unroll
  for (int j = 0; j < NPT; ++j) {
    float den[RR];
#pragma unroll
    for (int r = 0; r < RR; ++r) {
      float dv = EPSV;
#pragma unroll
      for (int t2 = 0; t2 < RR; ++t2) dv = fmaf(c[j][t2], btbl[t2 * 8 + r], dv);
      den[r] = dv;
    }
#pragma unroll
    for (int r = 0; r < RR; ++r) c[j][r] = c[j][r] * s[j][r] / den[r];
  }
  {
    float4* c4 = reinterpret_cast<float4*>(cp);
    c4[0] = make_float4(c[0][0], c[0][1], c[0][2], c[0][3]);
    c4[1] = make_float4(c[0][4], c[0][5], c[0][6], c[0][7]);
    c4[2] = make_float4(c[1][0], c[1][1], c[1][2], c[1][3]);
    c4[3] = make_float4(c[1][4], c[1][5], c[1][6], c[1][7]);
  }

  // ---- pass 2: numer2[d][r] += sum_n x[d][n]*cnew[n][r]
#pragma unroll 2
  for (int d = 0; d < DD; ++d) {
    const float2 xv = *reinterpret_cast<const float2*>(xb + (size_t)d * NN + n0);
    float p[RR];
#pragma unroll
    for (int r = 0; r < RR; ++r) p[r] = fmaf(xv.x, c[0][r], xv.y * c[1][r]);
    float v = wave_red(red8(p));
    if (lane < RR) nlds[wv][d][lane] = v;
  }
  // ---- CtC (once per thread)
#pragma unroll
  for (int r = 0; r < RR; ++r) {
    float p2[RR];
#pragma unroll
    for (int s2 = 0; s2 < RR; ++s2)
      p2[s2] = c[0][r] * c[0][s2] + c[1][r] * c[1][s2];
    float v = wave_red(red8(p2));
    if (lane < RR) ctcl[wv][r * 8 + lane] = v;
  }
  __syncthreads();

  const float* nf = &nlds[0][0][0];
  for (int i = tid; i < DD * RR; i += TPB) {
    float acc = nf[i] + nf[DD * RR + i] + nf[2 * DD * RR + i] + nf[3 * DD * RR + i];
    atomicAdd(&n2acc[b * DD * RR + i], acc);
  }
  if (tid < 64) {
    float acc = ctcl[0][tid] + ctcl[1][tid] + ctcl[2][tid] + ctcl[3][tid];
    atomicAdd(&ctcacc[b * 64 + tid], acc);
  }
}

// ---------------------------------------------------------------------------
// k_bases: bases = bases * numer2 / (bases@CtC + eps); recompute BtB;
//          zero accumulators for the next step. grid = BS, 128 threads.
// ---------------------------------------------------------------------------
__global__ __launch_bounds__(128) void k_bases(
    float* __restrict__ bases, float* __restrict__ btb,
    float* __restrict__ n2acc, float* __restrict__ ctcacc) {
  const int b = blockIdx.x;
  const int d = threadIdx.x;
  __shared__ float ctcs[64];
  __shared__ float bl[DD][RR];

  if (d < 64) ctcs[d] = ctcacc[b * 64 + d];
  __syncthreads();

  float row[RR], n2[RR];
  {
    const float4* r4 = reinterpret_cast<const float4*>(bases + ((size_t)b * DD + d) * RR);
    float4 x0 = r4[0], x1 = r4[1];
    row[0] = x0.x; row[1] = x0.y; row[2] = x0.z; row[3] = x0.w;
    row[4] = x1.x; row[5] = x1.y; row[6] = x1.z; row[7] = x1.w;
    const float4* n4 = reinterpret_cast<const float4*>(n2acc + ((size_t)b * DD + d) * RR);
    float4 y0 = n4[0], y1 = n4[1];
    n2[0] = y0.x; n2[1] = y0.y; n2[2] = y0.z; n2[3] = y0.w;
    n2[4] = y1.x; n2[5] = y1.y; n2[6] = y1.z; n2[7] = y1.w;
  }
  float nw[RR];
#pragma unroll
  for (int r = 0; r < RR; ++r) {
    float den = EPSV;
#pragma unroll
    for (int s2 = 0; s2 < RR; ++s2) den = fmaf(row[s2], ctcs[s2 * 8 + r], den);
    nw[r] = row[r] * n2[r] / den;
  }
  {
    float4* o4 = reinterpret_cast<float4*>(bases + ((size_t)b * DD + d) * RR);
    o4[0] = make_float4(nw[0], nw[1], nw[2], nw[3]);
    o4[1] = make_float4(nw[4], nw[5], nw[6], nw[7]);
    float4* z4 = reinterpret_cast<float4*>(n2acc + ((size_t)b * DD + d) * RR);
    z4[0] = make_float4(0.f, 0.f, 0.f, 0.f);
    z4[1] = make_float4(0.f, 0.f, 0.f, 0.f);
  }
#pragma unroll
  for (int r = 0; r < RR; ++r) bl[d][r] = nw[r];
  __syncthreads();
  if (d < 64) {
    const int r = d >> 3, s2 = d & 7;
    float acc = 0.f;
    for (int dd = 0; dd < DD; ++dd) acc += bl[dd][r] * bl[dd][s2];
    btb[b * 64 + d] = acc;
    ctcacc[b * 64 + d] = 0.f;
  }
}

// ---------------------------------------------------------------------------
// k_final: last coef update (compute_coef) fused with reconstruction
//          out = bases @ coef^T. grid = (NBLK, BS), TPB threads.
// ---------------------------------------------------------------------------
__global__ __launch_bounds__(TPB) void k_final(
    const float* __restrict__ xf, const float* __restrict__ coef,
    const float* __restrict__ bases, const float* __restrict__ btb,
    float* __restrict__ out) {
  const int b = blockIdx.y;
  const int tid = threadIdx.x;
  const size_t n0 = (size_t)blockIdx.x * NTILE + (size_t)tid * NPT;
  const float* __restrict__ xb = xf + (size_t)b * DD * NN;

  __shared__ float bl[DD][RR];
  __shared__ float btbl[RR * RR];

  reinterpret_cast<float4*>(&bl[0][0])[tid] =
      reinterpret_cast<const float4*>(bases + (size_t)b * DD * RR)[tid];
  if (tid < 64) btbl[tid] = btb[b * 64 + tid];
  __syncthreads();

  float s[NPT][RR];
#pragma unroll
  for (int j = 0; j < NPT; ++j)
#pragma unroll
    for (int r = 0; r < RR; ++r) s[j][r] = 0.f;

#pragma unroll 4
  for (int d = 0; d < DD; ++d) {
    const float2 xv = *reinterpret_cast<const float2*>(xb + (size_t)d * NN + n0);
    const float4 b03 = *reinterpret_cast<const float4*>(&bl[d][0]);
    const float4 b47 = *reinterpret_cast<const float4*>(&bl[d][4]);
    float bv[RR] = {b03.x, b03.y, b03.z, b03.w, b47.x, b47.y, b47.z, b47.w};
#pragma unroll
    for (int r = 0; r < RR; ++r) {
      s[0][r] = fmaf(xv.x, bv[r], s[0][r]);
      s[1][r] = fmaf(xv.y, bv[r], s[1][r]);
    }
  }

  const float* cp = coef + ((size_t)b * NN + n0) * RR;
  float c[NPT][RR];
  {
    const float4* c4 = reinterpret_cast<const float4*>(cp);
    float4 q0 = c4[0], q1 = c4[1], q2 = c4[2], q3 = c4[3];
    c[0][0] = q0.x; c[0][1] = q0.y; c[0][2] = q0.z; c[0][3] = q0.w;
    c[0][4] = q1.x; c[0][5] = q1.y; c[0][6] = q1.z; c[0][7] = q1.w;
    c[1][0] = q2.x; c[1][1] = q2.y; c[1][2] = q2.z; c[1][3] = q2.w;
    c[1][4] = q3.x; c[1][5] = q3.y; c[1][6] = q3.z; c[1][7] = q3.w;
  }
#pragma unroll
  for (int j = 0; j < NPT; ++j) {
    float den[RR];
#pragma unroll
    for (int r = 0; r < RR; ++r) {
      float dv = EPSV;
#pragma unroll
      for (int t2 = 0; t2 < RR; ++t2) dv = fmaf(c[j][t2], btbl[t2 * 8 + r], dv);
      den[r] = dv;
    }
#pragma unroll
    for (int r = 0; r < RR; ++r) c[j][r] = c[j][r] * s[j][r] / den[r];
  }

  float* ob = out + (size_t)b * DD * NN;
#pragma unroll 4
  for (int d = 0; d < DD; ++d) {
    const float4 b03 = *reinterpret_cast<const float4*>(&bl[d][0]);
    const float4 b47 = *reinterpret_cast<const float4*>(&bl[d][4]);
    float bv[RR] = {b03.x, b03.y, b03.z, b03.w, b47.x, b47.y, b47.z, b47.w};
    float ox = 0.f, oy = 0.f;
#pragma unroll
    for (int r = 0; r < RR; ++r) {
      ox = fmaf(bv[r], c[0][r], ox);
      oy = fmaf(bv[r], c[1][r], oy);
    }
    *reinterpret_cast<float2*>(ob + (size_t)d * NN + n0) = make_float2(ox, oy);
  }
}

// ---------------------------------------------------------------------------
extern "C" void kernel_launch(void* const* d_in, const int* in_sizes, int n_in,
                              void* d_out, int out_size, void* d_ws, size_t ws_size,
                              hipStream_t stream) {
  const float* x = (const float*)d_in[0];        // [BS, DD, NN] fp32 (reshape of x)
  const float* bi = (const float*)d_in[1];       // [BS, DD, RR] fp32
  float* out = (float*)d_out;                    // [BS, DD, NN] fp32

  // workspace layout (floats): coef | bases | btb | n2acc | ctcacc
  float* coef = (float*)d_ws;                         // BS*NN*RR
  float* bases = coef + (size_t)BS * NN * RR;         // BS*DD*RR
  float* btb = bases + (size_t)BS * DD * RR;          // BS*RR*RR
  float* n2acc = btb + (size_t)BS * RR * RR;          // BS*DD*RR
  float* ctcacc = n2acc + (size_t)BS * DD * RR;       // BS*RR*RR

  dim3 gbig(NBLK, BS);

  k_init<<<dim3(BS), 128, 0, stream>>>(bi, bases, btb, n2acc, ctcacc);

  // step 1 fused with the softmax init (same numer)
  k_step<true><<<gbig, TPB, 0, stream>>>(x, coef, bases, btb, n2acc, ctcacc);
  k_bases<<<dim3(BS), 128, 0, stream>>>(bases, btb, n2acc, ctcacc);

  // steps 2..6
  for (int it = 1; it < NSTEPS; ++it) {
    k_step<false><<<gbig, TPB, 0, stream>>>(x, coef, bases, btb, n2acc, ctcacc);
    k_bases<<<dim3(BS), 128, 0, stream>>>(bases, btb, n2acc, ctcacc);
  }

  // final coef update + reconstruction
  k_final<<<gbig, TPB, 0, stream>>>(x, coef, bases, btb, out);
}